// Round 7
// baseline (92.090 us; speedup 1.0000x reference)
//
#include <hip/hip_runtime.h>

// Problem constants (fixed by the reference)
constexpr int B = 8, T = 128, S = 256, H = 512;

typedef __attribute__((ext_vector_type(4))) float f32x4;
typedef __attribute__((ext_vector_type(8))) short short8;
typedef __attribute__((ext_vector_type(4))) short short4v;

#define DEVINL __device__ __forceinline__

DEVINL float bf2f(short s) {
  union { unsigned u; float f; } x;
  x.u = ((unsigned)(unsigned short)s) << 16;
  return x.f;
}
// fp32 -> bf16 round-to-nearest-even (finite inputs)
DEVINL short f2bf(float f) {
  unsigned u = __float_as_uint(f);
  return (short)((u + 0x7fffu + ((u >> 16) & 1u)) >> 16);
}
DEVINL float fast_tanh(float x) {
  float e = __builtin_amdgcn_exp2f(x * 2.8853900817779268f);
  return 1.0f - 2.0f * __builtin_amdgcn_rcpf(e + 1.0f);
}

constexpr float C2 = 2.8853900817779268f;   // 2*log2(e) — folded into W_s, W_h
constexpr float L2E = 1.4426950408889634f;  // log2(e)

// ---- workspace layout (units: shorts) — 9.5 MiB ----
constexpr size_t OFF_WSB = 0;                               // C2*W_s bf16  (H*H)
constexpr size_t OFF_WHB = OFF_WSB + (size_t)H * H;         // C2*W_h bf16  (H*H)
constexpr size_t OFF_WOB = OFF_WHB + (size_t)H * H;         // W_out bf16   (H*2H)
constexpr size_t OFF_EH  = OFF_WOB + (size_t)H * 2 * H;     // exp2(hs') PACKED [b][h/8][s][8] bf16 (B*H*S)
constexpr size_t OFF_ET  = OFF_EH + (size_t)B * H * S;      // enc^T bf16   (B*H*S)
constexpr size_t OFF_ATT = OFF_ET + (size_t)B * H * S;      // attn bf16    (B*T*S)
constexpr size_t OFF_CTX = OFF_ATT + (size_t)B * T * S;     // ctx bf16     (B*T*H)
constexpr size_t OFF_EQ  = OFF_CTX + (size_t)B * T * H;     // exp2(qs') f32 (B*T*H floats)

// ---- prep: blocks [0,256): enc f32 -> e_t[b][h][s] bf16 (LDS-tiled transpose);
//            blocks [256,1280): weights fp32 -> bf16 (W_s, W_h pre-scaled by C2) ----
__global__ __launch_bounds__(256) void prep_kernel(
    const float* __restrict__ ws, const float* __restrict__ wh,
    const float* __restrict__ wo, const float* __restrict__ enc,
    short* __restrict__ base) {
  __shared__ float tile[64][65];
  const int tid = threadIdx.x;
  if (blockIdx.x < 256) {
    short* e_t = base + OFF_ET;
    const int bid = blockIdx.x;
    const int b = bid >> 5;
    const int s0 = ((bid >> 3) & 3) * 64;
    const int h0 = (bid & 7) * 64;
#pragma unroll
    for (int p = 0; p < 4; ++p) {
      const int idx = p * 256 + tid;
      const int r = idx >> 4, c4 = (idx & 15) * 4;
      float4 f = *reinterpret_cast<const float4*>(&enc[(size_t)(b * S + s0 + r) * H + h0 + c4]);
      tile[r][c4 + 0] = f.x; tile[r][c4 + 1] = f.y; tile[r][c4 + 2] = f.z; tile[r][c4 + 3] = f.w;
    }
    __syncthreads();
#pragma unroll
    for (int p = 0; p < 2; ++p) {
      const int chunk = p * 256 + tid;
      const int rr = chunk >> 3, cc0 = (chunk & 7) * 8;
      short8 o;
#pragma unroll
      for (int j = 0; j < 8; ++j) o[j] = f2bf(tile[cc0 + j][rr]);
      *reinterpret_cast<short8*>(&e_t[(size_t)(b * H + h0 + rr) * S + s0 + cc0]) = o;
    }
  } else {
    int vi = (blockIdx.x - 256) * 256 + tid;  // vec4 index; Ws 65536 | Wh 65536 | Wo 131072
    if (vi >= 262144) return;
    const float* src; short* dst; int local; float scale;
    if (vi < 65536)       { src = ws; dst = base + OFF_WSB; local = vi;          scale = C2; }
    else if (vi < 131072) { src = wh; dst = base + OFF_WHB; local = vi - 65536;  scale = C2; }
    else                  { src = wo; dst = base + OFF_WOB; local = vi - 131072; scale = 1.f; }
    float4 f = reinterpret_cast<const float4*>(src)[local];
    short4v o;
    o.x = f2bf(f.x * scale); o.y = f2bf(f.y * scale);
    o.z = f2bf(f.z * scale); o.w = f2bf(f.w * scale);
    *reinterpret_cast<short4v*>(dst + (size_t)local * 4) = o;
  }
}

// ---- MFMA GEMM core: 128x64 tile (M x N), 256 thr = 4 waves (2x2), BK=64,
//      XOR-swizzled LDS. Wave (wm,wn) owns 64x32; frags mb=0..3, nb=0..1.
//      C[m][n] = sum_k A[m][k] * Wt[n][k]. ----
template <bool AF32>
DEVINL void gemm_tile(const void* __restrict__ Av, int lda,
                      const short* __restrict__ Wt, int ldw, int K,
                      int bm, int bn, short* As, short* Bs, f32x4 acc[4][2]) {
  const int tid = threadIdx.x;
  const int lane = tid & 63;
  const int wm = (tid >> 6) >> 1, wn = (tid >> 6) & 1;
  const int g = lane >> 4, r = lane & 15;
  for (int k0 = 0; k0 < K; k0 += 64) {
    __syncthreads();
    // stage A: 128 rows x 8 chunks = 1024 chunks
#pragma unroll
    for (int p = 0; p < 4; ++p) {
      const int idx = p * 256 + tid;
      const int row = idx >> 3, c = idx & 7;
      short8 av;
      if (AF32) {
        const float* Af = (const float*)Av;
        float4 f1 = *reinterpret_cast<const float4*>(&Af[(size_t)(bm + row) * lda + k0 + c * 8]);
        float4 f2 = *reinterpret_cast<const float4*>(&Af[(size_t)(bm + row) * lda + k0 + c * 8 + 4]);
        av[0] = f2bf(f1.x); av[1] = f2bf(f1.y); av[2] = f2bf(f1.z); av[3] = f2bf(f1.w);
        av[4] = f2bf(f2.x); av[5] = f2bf(f2.y); av[6] = f2bf(f2.z); av[7] = f2bf(f2.w);
      } else {
        const short* Ab = (const short*)Av;
        av = *reinterpret_cast<const short8*>(&Ab[(size_t)(bm + row) * lda + k0 + c * 8]);
      }
      *reinterpret_cast<short8*>(&As[row * 64 + ((c ^ (row & 7)) * 8)]) = av;
    }
    // stage B: 64 rows x 8 chunks = 512 chunks
#pragma unroll
    for (int p = 0; p < 2; ++p) {
      const int idx = p * 256 + tid;
      const int row = idx >> 3, c = idx & 7;
      short8 wv = *reinterpret_cast<const short8*>(&Wt[(size_t)(bn + row) * ldw + k0 + c * 8]);
      *reinterpret_cast<short8*>(&Bs[row * 64 + ((c ^ (row & 7)) * 8)]) = wv;
    }
    __syncthreads();
#pragma unroll
    for (int kc = 0; kc < 2; ++kc) {
      short8 af[4], bfr[2];
#pragma unroll
      for (int mb = 0; mb < 4; ++mb) {
        const int ra = wm * 64 + mb * 16 + r;
        af[mb] = *reinterpret_cast<const short8*>(&As[ra * 64 + (((kc * 4 + g) ^ (r & 7)) * 8)]);
      }
#pragma unroll
      for (int nb = 0; nb < 2; ++nb) {
        const int rb = wn * 32 + nb * 16 + r;
        bfr[nb] = *reinterpret_cast<const short8*>(&Bs[rb * 64 + (((kc * 4 + g) ^ (r & 7)) * 8)]);
      }
#pragma unroll
      for (int mb = 0; mb < 4; ++mb)
#pragma unroll
        for (int nb = 0; nb < 2; ++nb)
          acc[mb][nb] = __builtin_amdgcn_mfma_f32_16x16x32_bf16(af[mb], bfr[nb], acc[mb][nb], 0, 0, 0);
    }
  }
}

// blocks 0..63:   eq = exp2(query @ (C2*W_s)^T) -> f32 row-major [b*T+t][h]
// blocks 64..191: eh = exp2(enc @ (C2*W_h)^T)   -> bf16 PACKED [b][h/8][s][h%8]
__global__ __launch_bounds__(256) void gemm_proj_kernel(
    const float* __restrict__ query, const float* __restrict__ enc,
    const short* __restrict__ Wsb, const short* __restrict__ Whb,
    float* __restrict__ eq, short* __restrict__ eh_p) {
  __shared__ short As[128 * 64], Bs[64 * 64];
  f32x4 acc[4][2];
#pragma unroll
  for (int i = 0; i < 4; ++i)
#pragma unroll
    for (int j = 0; j < 2; ++j) acc[i][j] = (f32x4){0.f, 0.f, 0.f, 0.f};
  int bid = blockIdx.x;
  const bool is_q = bid < 64;
  const float* A; const short* Wt;
  if (is_q) { A = query; Wt = Wsb; }
  else      { bid -= 64; A = enc; Wt = Whb; }
  const int bm = (bid >> 3) * 128, bn = (bid & 7) * 64;
  gemm_tile<true>(A, H, Wt, H, H, bm, bn, As, Bs, acc);
  const int lane = threadIdx.x & 63, wave = threadIdx.x >> 6;
  const int wm = wave >> 1, wn = wave & 1, g = lane >> 4, r = lane & 15;
#pragma unroll
  for (int mb = 0; mb < 4; ++mb)
#pragma unroll
    for (int nb = 0; nb < 2; ++nb) {
      const int m0 = bm + wm * 64 + mb * 16 + g * 4;  // base of 4 consecutive rows
      const int col = bn + wn * 32 + nb * 16 + r;
      if (is_q) {
#pragma unroll
        for (int i = 0; i < 4; ++i)
          eq[(size_t)(m0 + i) * H + col] = __builtin_amdgcn_exp2f(acc[mb][nb][i]);
      } else {
        // rows are s-consecutive within one b (tile of 128 rows stays inside one b)
        const int bb = m0 >> 8, sl = m0 & 255;
        const size_t base = ((size_t)(bb * (H / 8) + (col >> 3)) * S + sl) * 8 + (col & 7);
#pragma unroll
        for (int i = 0; i < 4; ++i)
          eh_p[base + (size_t)i * 8] = f2bf(__builtin_amdgcn_exp2f(acc[mb][nb][i]));
      }
    }
}

// ---- scores + softmax -> attn bf16.
// Block = one t-row: 512 thr = 8 waves = 4 s-groups x 2 H-halves. Lane owns s=sg*64+lane.
// tanh(q+h) = 1 - 2*rcp(fma(eq,eh,1)); Sum_h v_h dropped (softmax shift-invariance).
// eh PACKED [b][h/8][s][8]: ONE short8 load per 8 h-elems per lane (coalesced 1KB/wave).
__global__ __launch_bounds__(512) void attn_kernel(
    const float* __restrict__ eq, const short* __restrict__ eh_p,
    const float* __restrict__ v, const int* __restrict__ lens,
    short* __restrict__ attn_bf) {
  __shared__ float s_part[2][S];
  __shared__ float red_m[4], red_s[4];
  const int tid = threadIdx.x, lane = tid & 63, wave = tid >> 6;
  const int sg = wave & 3, half = wave >> 2;
  const int b = blockIdx.x >> 7;           // T = 128 blocks per batch
  const int t = blockIdx.x & 127;
  const int s = sg * 64 + lane;

  const float* qp = eq + (size_t)(b * T + t) * H + half * (H / 2);
  const float* vp = v + half * (H / 2);
  const short* ep = eh_p + ((size_t)(b * (H / 8) + half * (H / 16)) * S + s) * 8;

  float a0 = 0.f, a1 = 0.f;
  for (int ch = 0; ch < H / 16; ++ch) {    // 32 chunks of 8 h-elems over this half
    const int h = ch * 8;
    const short8 ev = *reinterpret_cast<const short8*>(ep + (size_t)ch * S * 8);
    const f32x4 qa = *reinterpret_cast<const f32x4*>(qp + h);
    const f32x4 qb = *reinterpret_cast<const f32x4*>(qp + h + 4);
    const f32x4 va = *reinterpret_cast<const f32x4*>(vp + h);
    const f32x4 vb = *reinterpret_cast<const f32x4*>(vp + h + 4);
#pragma unroll
    for (int j = 0; j < 4; ++j) {
      float e0 = bf2f(ev[j]);
      float e1 = bf2f(ev[j + 4]);
      a0 = fmaf(va[j], __builtin_amdgcn_rcpf(fmaf(qa[j], e0, 1.0f)), a0);
      a1 = fmaf(vb[j], __builtin_amdgcn_rcpf(fmaf(qb[j], e1, 1.0f)), a1);
    }
  }
  s_part[half][s] = a0 + a1;
  __syncthreads();

  // all 8 waves redundantly finalize (uniform control flow; identical values)
  const float acc = s_part[0][s] + s_part[1][s];
  const int len = lens[b];
  const float y = (s < len) ? (-2.0f * L2E * acc) : -1e30f;  // log2-domain score

  float m = y;
#pragma unroll
  for (int off = 32; off > 0; off >>= 1) m = fmaxf(m, __shfl_xor(m, off));
  if (lane == 0) red_m[sg] = m;   // both halves write identical value
  __syncthreads();
  const float mt = fmaxf(fmaxf(red_m[0], red_m[1]), fmaxf(red_m[2], red_m[3]));
  const float p = __builtin_amdgcn_exp2f(y - mt);
  float sum = p;
#pragma unroll
  for (int off = 32; off > 0; off >>= 1) sum += __shfl_xor(sum, off);
  if (lane == 0) red_s[sg] = sum;
  __syncthreads();
  if (half == 0) {
    const float tot = red_s[0] + red_s[1] + red_s[2] + red_s[3];
    attn_bf[(size_t)(b * T + t) * S + s] = f2bf(p * __builtin_amdgcn_rcpf(tot));
  }
}

// ctx = attn @ enc  (via e_t as Wt). A rows: [B*T][S]; Wt rows: e_t[b][h][s].
__global__ __launch_bounds__(256) void ctx_gemm_kernel(
    const short* __restrict__ attn_bf, const short* __restrict__ e_t,
    short* __restrict__ ctx_bf) {
  __shared__ short As[128 * 64], Bs[64 * 64];
  f32x4 acc[4][2];
#pragma unroll
  for (int i = 0; i < 4; ++i)
#pragma unroll
    for (int j = 0; j < 2; ++j) acc[i][j] = (f32x4){0.f, 0.f, 0.f, 0.f};
  const int bm = blockIdx.x * 128;         // over B*T = 1024 rows
  const int bn = blockIdx.y * 64;          // over H
  const int batch = bm >> 7;               // T = 128 rows per batch
  gemm_tile<false>(attn_bf, S, e_t + (size_t)batch * H * S, S, S, bm, bn, As, Bs, acc);
  const int lane = threadIdx.x & 63, wave = threadIdx.x >> 6;
  const int wm = wave >> 1, wn = wave & 1, g = lane >> 4, r = lane & 15;
#pragma unroll
  for (int mb = 0; mb < 4; ++mb)
#pragma unroll
    for (int nb = 0; nb < 2; ++nb)
#pragma unroll
      for (int i = 0; i < 4; ++i) {
        const int row = bm + wm * 64 + mb * 16 + g * 4 + i;
        const int col = bn + wn * 32 + nb * 16 + r;
        ctx_bf[(size_t)row * H + col] = f2bf(acc[mb][nb][i]);
      }
}

// out = tanh([ctx | query] @ W_out^T + b_out), f32 out.
__global__ __launch_bounds__(256) void gemm_out_kernel(
    const short* __restrict__ ctx_bf, const float* __restrict__ query,
    const short* __restrict__ Wob, const float* __restrict__ bias,
    float* __restrict__ out) {
  __shared__ short As[128 * 64], Bs[64 * 64];
  f32x4 acc[4][2];
#pragma unroll
  for (int i = 0; i < 4; ++i)
#pragma unroll
    for (int j = 0; j < 2; ++j) acc[i][j] = (f32x4){0.f, 0.f, 0.f, 0.f};
  const int bm = (blockIdx.x >> 3) * 128, bn = (blockIdx.x & 7) * 64;
  gemm_tile<false>(ctx_bf, H, Wob, 2 * H, H, bm, bn, As, Bs, acc);
  gemm_tile<true>(query, H, Wob + H, 2 * H, H, bm, bn, As, Bs, acc);
  const int lane = threadIdx.x & 63, wave = threadIdx.x >> 6;
  const int wm = wave >> 1, wn = wave & 1, g = lane >> 4, r = lane & 15;
#pragma unroll
  for (int mb = 0; mb < 4; ++mb)
#pragma unroll
    for (int nb = 0; nb < 2; ++nb) {
      const int col = bn + wn * 32 + nb * 16 + r;
      const float bb = bias[col];
#pragma unroll
      for (int i = 0; i < 4; ++i) {
        const int row = bm + wm * 64 + mb * 16 + g * 4 + i;
        out[(size_t)row * H + col] = fast_tanh(acc[mb][nb][i] + bb);
      }
    }
}

extern "C" void kernel_launch(void* const* d_in, const int* in_sizes, int n_in,
                              void* d_out, int out_size, void* d_ws, size_t ws_size,
                              hipStream_t stream) {
  const float* query = (const float*)d_in[0];  // (B,T,H)
  const float* enc = (const float*)d_in[1];    // (B,S,H)
  const int* lens = (const int*)d_in[2];       // (B)
  const float* W_s = (const float*)d_in[3];    // (H,H)
  const float* W_h = (const float*)d_in[4];    // (H,H)
  const float* v = (const float*)d_in[5];      // (H)
  const float* W_out = (const float*)d_in[6];  // (H,2H)
  const float* b_out = (const float*)d_in[7];  // (H)
  float* out = (float*)d_out;                  // (B,T,H)

  short* wsb = (short*)d_ws;
  short* Wsb = wsb + OFF_WSB;
  short* Whb = wsb + OFF_WHB;
  short* Wob = wsb + OFF_WOB;
  short* eh_p = wsb + OFF_EH;
  short* e_t = wsb + OFF_ET;
  short* attn_bf = wsb + OFF_ATT;
  short* ctx_bf = wsb + OFF_CTX;
  float* eq = (float*)(wsb + OFF_EQ);

  prep_kernel<<<1280, 256, 0, stream>>>(W_s, W_h, W_out, enc, wsb);
  gemm_proj_kernel<<<192, 256, 0, stream>>>(query, enc, Wsb, Whb, eq, eh_p);
  attn_kernel<<<B * T, 512, 0, stream>>>(eq, eh_p, v, lens, attn_bf);
  ctx_gemm_kernel<<<dim3(8, 8), 256, 0, stream>>>(attn_bf, e_t, ctx_bf);
  gemm_out_kernel<<<64, 256, 0, stream>>>(ctx_bf, query, Wob, b_out, out);
}

// Round 8
// 70.472 us; speedup vs baseline: 1.3068x; 1.3068x over previous
//
#include <hip/hip_runtime.h>

// Problem constants (fixed by the reference)
constexpr int B = 8, T = 128, S = 256, H = 512;

typedef __attribute__((ext_vector_type(4))) float f32x4;
typedef __attribute__((ext_vector_type(8))) float f32x8;
typedef __attribute__((ext_vector_type(8))) short short8;
typedef __attribute__((ext_vector_type(4))) short short4v;

#define DEVINL __device__ __forceinline__

DEVINL float bf2f(short s) {
  union { unsigned u; float f; } x;
  x.u = ((unsigned)(unsigned short)s) << 16;
  return x.f;
}
// fp32 -> bf16 round-to-nearest-even (finite inputs)
DEVINL short f2bf(float f) {
  unsigned u = __float_as_uint(f);
  return (short)((u + 0x7fffu + ((u >> 16) & 1u)) >> 16);
}
DEVINL float fast_tanh(float x) {
  float e = __builtin_amdgcn_exp2f(x * 2.8853900817779268f);
  return 1.0f - 2.0f * __builtin_amdgcn_rcpf(e + 1.0f);
}

constexpr float C2 = 2.8853900817779268f;   // 2*log2(e) — folded into W_s, W_h at staging
constexpr float L2E = 1.4426950408889634f;  // log2(e)

// ---- workspace layout (units: shorts) — 7.5 MiB ----
constexpr size_t OFF_EH  = 0;                               // exp2(hs') PACKED [b][h/8][s][8] bf16 (B*H*S)
constexpr size_t OFF_ET  = OFF_EH + (size_t)B * H * S;      // enc^T bf16 [b][h][s] (B*H*S)
constexpr size_t OFF_ATT = OFF_ET + (size_t)B * H * S;      // attn bf16    (B*T*S)
constexpr size_t OFF_CTX = OFF_ATT + (size_t)B * T * S;     // ctx bf16     (B*T*H)
constexpr size_t OFF_EQ  = OFF_CTX + (size_t)B * T * H;     // exp2(qs') f32 (B*T*H floats)

// ---- MFMA GEMM core: 64x64 tile, 256 thr (4 waves 2x2), BK=64, XOR-swizzled LDS.
//      C[m][n] = sum_k A[m][k] * (wscale*W[n][k]). A,W each bf16 or f32 (converted at staging).
template <bool AF32, bool WF32>
DEVINL void gemm_tile(const void* __restrict__ Av, int lda,
                      const void* __restrict__ Wv, int ldw, int K, float wscale,
                      int bm, int bn, short* As, short* Bs, f32x4 acc[2][2]) {
  const int tid = threadIdx.x;
  const int lane = tid & 63;
  const int wm = (tid >> 6) >> 1, wn = (tid >> 6) & 1;
  const int g = lane >> 4, r = lane & 15;
  for (int k0 = 0; k0 < K; k0 += 64) {
    __syncthreads();
#pragma unroll
    for (int p = 0; p < 2; ++p) {
      const int idx = p * 256 + tid;
      const int row = idx >> 3, c = idx & 7;
      short8 av;
      if (AF32) {
        const float* Af = (const float*)Av;
        float4 f1 = *reinterpret_cast<const float4*>(&Af[(size_t)(bm + row) * lda + k0 + c * 8]);
        float4 f2 = *reinterpret_cast<const float4*>(&Af[(size_t)(bm + row) * lda + k0 + c * 8 + 4]);
        av[0] = f2bf(f1.x); av[1] = f2bf(f1.y); av[2] = f2bf(f1.z); av[3] = f2bf(f1.w);
        av[4] = f2bf(f2.x); av[5] = f2bf(f2.y); av[6] = f2bf(f2.z); av[7] = f2bf(f2.w);
      } else {
        av = *reinterpret_cast<const short8*>(&((const short*)Av)[(size_t)(bm + row) * lda + k0 + c * 8]);
      }
      short8 wv;
      if (WF32) {
        const float* Wf = (const float*)Wv;
        float4 f1 = *reinterpret_cast<const float4*>(&Wf[(size_t)(bn + row) * ldw + k0 + c * 8]);
        float4 f2 = *reinterpret_cast<const float4*>(&Wf[(size_t)(bn + row) * ldw + k0 + c * 8 + 4]);
        wv[0] = f2bf(f1.x * wscale); wv[1] = f2bf(f1.y * wscale);
        wv[2] = f2bf(f1.z * wscale); wv[3] = f2bf(f1.w * wscale);
        wv[4] = f2bf(f2.x * wscale); wv[5] = f2bf(f2.y * wscale);
        wv[6] = f2bf(f2.z * wscale); wv[7] = f2bf(f2.w * wscale);
      } else {
        wv = *reinterpret_cast<const short8*>(&((const short*)Wv)[(size_t)(bn + row) * ldw + k0 + c * 8]);
      }
      *reinterpret_cast<short8*>(&As[row * 64 + ((c ^ (row & 7)) * 8)]) = av;
      *reinterpret_cast<short8*>(&Bs[row * 64 + ((c ^ (row & 7)) * 8)]) = wv;
    }
    __syncthreads();
#pragma unroll
    for (int kc = 0; kc < 2; ++kc) {
      short8 af[2], bfr[2];
#pragma unroll
      for (int mb = 0; mb < 2; ++mb) {
        const int ra = wm * 32 + mb * 16 + r;
        af[mb] = *reinterpret_cast<const short8*>(&As[ra * 64 + (((kc * 4 + g) ^ (r & 7)) * 8)]);
      }
#pragma unroll
      for (int nb = 0; nb < 2; ++nb) {
        const int rb = wn * 32 + nb * 16 + r;
        bfr[nb] = *reinterpret_cast<const short8*>(&Bs[rb * 64 + (((kc * 4 + g) ^ (r & 7)) * 8)]);
      }
#pragma unroll
      for (int mb = 0; mb < 2; ++mb)
#pragma unroll
        for (int nb = 0; nb < 2; ++nb)
          acc[mb][nb] = __builtin_amdgcn_mfma_f32_16x16x32_bf16(af[mb], bfr[nb], acc[mb][nb], 0, 0, 0);
    }
  }
}

// K1: blocks 0..127:   eq = exp2(query @ (C2*W_s)^T) -> f32 [b*T+t][h]
//     blocks 128..383: eh = exp2(enc @ (C2*W_h)^T)   -> bf16 PACKED [b][h/8][s][h%8]
//     blocks 384..639: enc f32 -> e_t[b][h][s] bf16 (LDS-tiled transpose)
__global__ __launch_bounds__(256) void proj_kernel(
    const float* __restrict__ query, const float* __restrict__ enc,
    const float* __restrict__ Ws, const float* __restrict__ Wh,
    short* __restrict__ wsbase, float* __restrict__ eq) {
  __shared__ __align__(16) char smem[16640];
  const int tid = threadIdx.x;
  if (blockIdx.x >= 384) {  // ---- transpose branch ----
    float (*tile)[65] = (float(*)[65])smem;
    short* e_t = wsbase + OFF_ET;
    const int bid = blockIdx.x - 384;
    const int b = bid >> 5;
    const int s0 = ((bid >> 3) & 3) * 64;
    const int h0 = (bid & 7) * 64;
#pragma unroll
    for (int p = 0; p < 4; ++p) {
      const int idx = p * 256 + tid;
      const int r = idx >> 4, c4 = (idx & 15) * 4;
      float4 f = *reinterpret_cast<const float4*>(&enc[(size_t)(b * S + s0 + r) * H + h0 + c4]);
      tile[r][c4 + 0] = f.x; tile[r][c4 + 1] = f.y; tile[r][c4 + 2] = f.z; tile[r][c4 + 3] = f.w;
    }
    __syncthreads();
#pragma unroll
    for (int p = 0; p < 2; ++p) {
      const int chunk = p * 256 + tid;
      const int rr = chunk >> 3, cc0 = (chunk & 7) * 8;
      short8 o;
#pragma unroll
      for (int j = 0; j < 8; ++j) o[j] = f2bf(tile[cc0 + j][rr]);
      *reinterpret_cast<short8*>(&e_t[(size_t)(b * H + h0 + rr) * S + s0 + cc0]) = o;
    }
    return;
  }
  // ---- GEMM branch ----
  short* As = (short*)smem;
  short* Bs = As + 64 * 64;
  f32x4 acc[2][2];
#pragma unroll
  for (int i = 0; i < 2; ++i)
#pragma unroll
    for (int j = 0; j < 2; ++j) acc[i][j] = (f32x4){0.f, 0.f, 0.f, 0.f};
  int bid = blockIdx.x;
  const bool is_q = bid < 128;
  const float* A; const float* W;
  if (is_q) { A = query; W = Ws; }
  else      { bid -= 128; A = enc; W = Wh; }
  const int bm = (bid >> 3) * 64, bn = (bid & 7) * 64;
  gemm_tile<true, true>(A, H, W, H, H, C2, bm, bn, As, Bs, acc);
  short* eh_p = wsbase + OFF_EH;
  const int lane = threadIdx.x & 63, wave = threadIdx.x >> 6;
  const int wm = wave >> 1, wn = wave & 1, g = lane >> 4, r = lane & 15;
#pragma unroll
  for (int mb = 0; mb < 2; ++mb)
#pragma unroll
    for (int nb = 0; nb < 2; ++nb) {
      const int m0 = bm + wm * 32 + mb * 16 + g * 4;  // base of 4 consecutive rows
      const int col = bn + wn * 32 + nb * 16 + r;
      if (is_q) {
#pragma unroll
        for (int i = 0; i < 4; ++i)
          eq[(size_t)(m0 + i) * H + col] = __builtin_amdgcn_exp2f(acc[mb][nb][i]);
      } else {
        // rows are s-consecutive within one b (64-row tile stays inside one b)
        const int bb = m0 >> 8, sl = m0 & 255;
        const size_t base = ((size_t)(bb * (H / 8) + (col >> 3)) * S + sl) * 8 + (col & 7);
#pragma unroll
        for (int i = 0; i < 4; ++i)
          eh_p[base + (size_t)i * 8] = f2bf(__builtin_amdgcn_exp2f(acc[mb][nb][i]));
      }
    }
}

// K2: scores + softmax -> attn bf16.
// Block = 2 t-rows: 512 thr = 8 waves = 4 s-groups x 2 H-halves; lane owns s=sg*64+lane,
// and BOTH t-rows (eh load shared across t). q/v pointers are wave-uniform (readfirstlane)
// -> scalar s_load on the SMEM pipe; eh is the only VMEM stream (prefetch depth 2).
// tanh(q+h) = 1 - 2*rcp(fma(eq,eh,1)); Sum_h v_h dropped (softmax shift-invariance).
__global__ __launch_bounds__(512) void attn_kernel(
    const float* __restrict__ eq, const short* __restrict__ eh_p,
    const float* __restrict__ v, const int* __restrict__ lens,
    short* __restrict__ attn_bf) {
  __shared__ float s_part[2][2][S];            // [half][tt][s]
  __shared__ float red_m[2][4], red_s[2][4];   // [tt][sg]
  const int tid = threadIdx.x, lane = tid & 63;
  const int wu = __builtin_amdgcn_readfirstlane(tid >> 6);  // uniform wave id -> SGPR
  const int sg = wu & 3, half = wu >> 2;
  const int b = blockIdx.x >> 6;               // 64 blocks per batch (T/2)
  const int t0 = (blockIdx.x & 63) * 2;
  const int s = sg * 64 + lane;

  const float* qp0 = eq + (size_t)(b * T + t0) * H + half * (H / 2);  // uniform
  const float* qp1 = qp0 + H;                                          // uniform
  const float* vp = v + half * (H / 2);                                // uniform
  const short8* epp = reinterpret_cast<const short8*>(eh_p) +
                      ((size_t)(b * (H / 8) + half * (H / 16)) * S + s);

  float acc0 = 0.f, acc1 = 0.f;
  short8 ev0 = epp[0];
  short8 ev1 = epp[S];
  for (int ch = 0; ch < 32; ++ch) {
    const short8 evn = (ch < 30) ? epp[(size_t)(ch + 2) * S] : ev0;
    const int h = ch * 8;
    const f32x8 q0 = *reinterpret_cast<const f32x8*>(qp0 + h);  // s_load_dwordx8
    const f32x8 q1 = *reinterpret_cast<const f32x8*>(qp1 + h);
    const f32x8 vv = *reinterpret_cast<const f32x8*>(vp + h);
#pragma unroll
    for (int j = 0; j < 8; ++j) {
      const float e = bf2f(ev0[j]);
      acc0 = fmaf(vv[j], __builtin_amdgcn_rcpf(fmaf(q0[j], e, 1.0f)), acc0);
      acc1 = fmaf(vv[j], __builtin_amdgcn_rcpf(fmaf(q1[j], e, 1.0f)), acc1);
    }
    ev0 = ev1; ev1 = evn;
  }
  s_part[half][0][s] = acc0;
  s_part[half][1][s] = acc1;
  __syncthreads();

  // all 8 waves redundantly finalize (uniform control flow; identical values)
  const int len = lens[b];
  const float a0 = s_part[0][0][s] + s_part[1][0][s];
  const float a1 = s_part[0][1][s] + s_part[1][1][s];
  const float y0 = (s < len) ? (-2.0f * L2E * a0) : -1e30f;  // log2-domain scores
  const float y1 = (s < len) ? (-2.0f * L2E * a1) : -1e30f;
  float m0 = y0, m1 = y1;
#pragma unroll
  for (int off = 32; off > 0; off >>= 1) {
    m0 = fmaxf(m0, __shfl_xor(m0, off));
    m1 = fmaxf(m1, __shfl_xor(m1, off));
  }
  if (lane == 0) { red_m[0][sg] = m0; red_m[1][sg] = m1; }
  __syncthreads();
  const float mt0 = fmaxf(fmaxf(red_m[0][0], red_m[0][1]), fmaxf(red_m[0][2], red_m[0][3]));
  const float mt1 = fmaxf(fmaxf(red_m[1][0], red_m[1][1]), fmaxf(red_m[1][2], red_m[1][3]));
  const float p0 = __builtin_amdgcn_exp2f(y0 - mt0);
  const float p1 = __builtin_amdgcn_exp2f(y1 - mt1);
  float u0 = p0, u1 = p1;
#pragma unroll
  for (int off = 32; off > 0; off >>= 1) {
    u0 += __shfl_xor(u0, off);
    u1 += __shfl_xor(u1, off);
  }
  if (lane == 0) { red_s[0][sg] = u0; red_s[1][sg] = u1; }
  __syncthreads();
  if (half == 0) {
    const float tot0 = red_s[0][0] + red_s[0][1] + red_s[0][2] + red_s[0][3];
    const float tot1 = red_s[1][0] + red_s[1][1] + red_s[1][2] + red_s[1][3];
    attn_bf[(size_t)(b * T + t0) * S + s] = f2bf(p0 * __builtin_amdgcn_rcpf(tot0));
    attn_bf[(size_t)(b * T + t0 + 1) * S + s] = f2bf(p1 * __builtin_amdgcn_rcpf(tot1));
  }
}

// K3: ctx = attn @ enc  (via e_t as Wt). A rows: [B*T][S]; Wt rows: e_t[b][h][s].
__global__ __launch_bounds__(256) void ctx_gemm_kernel(
    const short* __restrict__ attn_bf, const short* __restrict__ e_t,
    short* __restrict__ ctx_bf) {
  __shared__ short As[64 * 64], Bs[64 * 64];
  f32x4 acc[2][2];
#pragma unroll
  for (int i = 0; i < 2; ++i)
#pragma unroll
    for (int j = 0; j < 2; ++j) acc[i][j] = (f32x4){0.f, 0.f, 0.f, 0.f};
  const int bm = blockIdx.x * 64;          // over B*T = 1024 rows
  const int bn = blockIdx.y * 64;          // over H
  const int batch = bm >> 7;               // T = 128 rows per batch
  gemm_tile<false, false>(attn_bf, S, e_t + (size_t)batch * H * S, S, S, 1.f,
                          bm, bn, As, Bs, acc);
  const int lane = threadIdx.x & 63, wave = threadIdx.x >> 6;
  const int wm = wave >> 1, wn = wave & 1, g = lane >> 4, r = lane & 15;
#pragma unroll
  for (int mb = 0; mb < 2; ++mb)
#pragma unroll
    for (int nb = 0; nb < 2; ++nb)
#pragma unroll
      for (int i = 0; i < 4; ++i) {
        const int row = bm + wm * 32 + mb * 16 + g * 4 + i;
        const int col = bn + wn * 32 + nb * 16 + r;
        ctx_bf[(size_t)row * H + col] = f2bf(acc[mb][nb][i]);
      }
}

// K4: out = tanh([ctx | query] @ W_out^T + b_out), f32 out. W_out read f32 directly.
__global__ __launch_bounds__(256) void gemm_out_kernel(
    const short* __restrict__ ctx_bf, const float* __restrict__ query,
    const float* __restrict__ Wo, const float* __restrict__ bias,
    float* __restrict__ out) {
  __shared__ short As[64 * 64], Bs[64 * 64];
  f32x4 acc[2][2];
#pragma unroll
  for (int i = 0; i < 2; ++i)
#pragma unroll
    for (int j = 0; j < 2; ++j) acc[i][j] = (f32x4){0.f, 0.f, 0.f, 0.f};
  const int bm = (blockIdx.x >> 3) * 64, bn = (blockIdx.x & 7) * 64;
  gemm_tile<false, true>(ctx_bf, H, Wo, 2 * H, H, 1.f, bm, bn, As, Bs, acc);
  gemm_tile<true, true>(query, H, Wo + H, 2 * H, H, 1.f, bm, bn, As, Bs, acc);
  const int lane = threadIdx.x & 63, wave = threadIdx.x >> 6;
  const int wm = wave >> 1, wn = wave & 1, g = lane >> 4, r = lane & 15;
#pragma unroll
  for (int mb = 0; mb < 2; ++mb)
#pragma unroll
    for (int nb = 0; nb < 2; ++nb) {
      const int col = bn + wn * 32 + nb * 16 + r;
      const float bb = bias[col];
#pragma unroll
      for (int i = 0; i < 4; ++i) {
        const int row = bm + wm * 32 + mb * 16 + g * 4 + i;
        out[(size_t)row * H + col] = fast_tanh(acc[mb][nb][i] + bb);
      }
    }
}

extern "C" void kernel_launch(void* const* d_in, const int* in_sizes, int n_in,
                              void* d_out, int out_size, void* d_ws, size_t ws_size,
                              hipStream_t stream) {
  const float* query = (const float*)d_in[0];  // (B,T,H)
  const float* enc = (const float*)d_in[1];    // (B,S,H)
  const int* lens = (const int*)d_in[2];       // (B)
  const float* W_s = (const float*)d_in[3];    // (H,H)
  const float* W_h = (const float*)d_in[4];    // (H,H)
  const float* v = (const float*)d_in[5];      // (H)
  const float* W_out = (const float*)d_in[6];  // (H,2H)
  const float* b_out = (const float*)d_in[7];  // (H)
  float* out = (float*)d_out;                  // (B,T,H)

  short* wsb = (short*)d_ws;
  short* eh_p = wsb + OFF_EH;
  short* e_t = wsb + OFF_ET;
  short* attn_bf = wsb + OFF_ATT;
  short* ctx_bf = wsb + OFF_CTX;
  float* eq = (float*)(wsb + OFF_EQ);

  proj_kernel<<<640, 256, 0, stream>>>(query, enc, W_s, W_h, wsb, eq);
  attn_kernel<<<B * T / 2, 512, 0, stream>>>(eq, eh_p, v, lens, attn_bf);
  ctx_gemm_kernel<<<dim3(16, 8), 256, 0, stream>>>(attn_bf, e_t, ctx_bf);
  gemm_out_kernel<<<128, 256, 0, stream>>>(ctx_bf, query, W_out, b_out, out);
}

// Round 9
// 61.104 us; speedup vs baseline: 1.5071x; 1.1533x over previous
//
#include <hip/hip_runtime.h>

// Problem constants (fixed by the reference)
constexpr int B = 8, T = 128, S = 256, H = 512;

typedef __attribute__((ext_vector_type(4))) float f32x4;
typedef __attribute__((ext_vector_type(8))) float f32x8;
typedef __attribute__((ext_vector_type(8))) short short8;
typedef __attribute__((ext_vector_type(4))) short short4v;

#define DEVINL __device__ __forceinline__

DEVINL float bf2f(short s) {
  union { unsigned u; float f; } x;
  x.u = ((unsigned)(unsigned short)s) << 16;
  return x.f;
}
// fp32 -> bf16 round-to-nearest-even (finite inputs)
DEVINL short f2bf(float f) {
  unsigned u = __float_as_uint(f);
  return (short)((u + 0x7fffu + ((u >> 16) & 1u)) >> 16);
}
DEVINL float fast_tanh(float x) {
  float e = __builtin_amdgcn_exp2f(x * 2.8853900817779268f);
  return 1.0f - 2.0f * __builtin_amdgcn_rcpf(e + 1.0f);
}

constexpr float C2 = 2.8853900817779268f;   // 2*log2(e) — folded into W_s, W_h at staging
constexpr float L2E = 1.4426950408889634f;  // log2(e)

// ---- workspace layout (units: shorts) — 6.5 MiB ----
constexpr size_t OFF_EH  = 0;                               // exp2(hs') PACKED [b][h/8][s][8] bf16 (B*H*S)
constexpr size_t OFF_PT  = OFF_EH + (size_t)B * H * S;      // P^T = (enc@W1^T)^T bf16 [b][n][s] (B*H*S)
constexpr size_t OFF_ATT = OFF_PT + (size_t)B * H * S;      // attn bf16    (B*T*S)
constexpr size_t OFF_EQ  = OFF_ATT + (size_t)B * T * S;     // exp2(qs') f32 (B*T*H floats)

// ---- MFMA GEMM core: 64x64 tile, 256 thr (4 waves 2x2), BK=64, XOR-swizzled LDS.
//      C[m][n] = sum_k A[m][k] * (wscale*W[n][k]). A,W each bf16 or f32 (converted at staging).
template <bool AF32, bool WF32>
DEVINL void gemm_tile(const void* __restrict__ Av, int lda,
                      const void* __restrict__ Wv, int ldw, int K, float wscale,
                      int bm, int bn, short* As, short* Bs, f32x4 acc[2][2]) {
  const int tid = threadIdx.x;
  const int lane = tid & 63;
  const int wm = (tid >> 6) >> 1, wn = (tid >> 6) & 1;
  const int g = lane >> 4, r = lane & 15;
  for (int k0 = 0; k0 < K; k0 += 64) {
    __syncthreads();
#pragma unroll
    for (int p = 0; p < 2; ++p) {
      const int idx = p * 256 + tid;
      const int row = idx >> 3, c = idx & 7;
      short8 av;
      if (AF32) {
        const float* Af = (const float*)Av;
        float4 f1 = *reinterpret_cast<const float4*>(&Af[(size_t)(bm + row) * lda + k0 + c * 8]);
        float4 f2 = *reinterpret_cast<const float4*>(&Af[(size_t)(bm + row) * lda + k0 + c * 8 + 4]);
        av[0] = f2bf(f1.x); av[1] = f2bf(f1.y); av[2] = f2bf(f1.z); av[3] = f2bf(f1.w);
        av[4] = f2bf(f2.x); av[5] = f2bf(f2.y); av[6] = f2bf(f2.z); av[7] = f2bf(f2.w);
      } else {
        av = *reinterpret_cast<const short8*>(&((const short*)Av)[(size_t)(bm + row) * lda + k0 + c * 8]);
      }
      short8 wv;
      if (WF32) {
        const float* Wf = (const float*)Wv;
        float4 f1 = *reinterpret_cast<const float4*>(&Wf[(size_t)(bn + row) * ldw + k0 + c * 8]);
        float4 f2 = *reinterpret_cast<const float4*>(&Wf[(size_t)(bn + row) * ldw + k0 + c * 8 + 4]);
        wv[0] = f2bf(f1.x * wscale); wv[1] = f2bf(f1.y * wscale);
        wv[2] = f2bf(f1.z * wscale); wv[3] = f2bf(f1.w * wscale);
        wv[4] = f2bf(f2.x * wscale); wv[5] = f2bf(f2.y * wscale);
        wv[6] = f2bf(f2.z * wscale); wv[7] = f2bf(f2.w * wscale);
      } else {
        wv = *reinterpret_cast<const short8*>(&((const short*)Wv)[(size_t)(bn + row) * ldw + k0 + c * 8]);
      }
      *reinterpret_cast<short8*>(&As[row * 64 + ((c ^ (row & 7)) * 8)]) = av;
      *reinterpret_cast<short8*>(&Bs[row * 64 + ((c ^ (row & 7)) * 8)]) = wv;
    }
    __syncthreads();
#pragma unroll
    for (int kc = 0; kc < 2; ++kc) {
      short8 af[2], bfr[2];
#pragma unroll
      for (int mb = 0; mb < 2; ++mb) {
        const int ra = wm * 32 + mb * 16 + r;
        af[mb] = *reinterpret_cast<const short8*>(&As[ra * 64 + (((kc * 4 + g) ^ (r & 7)) * 8)]);
      }
#pragma unroll
      for (int nb = 0; nb < 2; ++nb) {
        const int rb = wn * 32 + nb * 16 + r;
        bfr[nb] = *reinterpret_cast<const short8*>(&Bs[rb * 64 + (((kc * 4 + g) ^ (r & 7)) * 8)]);
      }
#pragma unroll
      for (int mb = 0; mb < 2; ++mb)
#pragma unroll
        for (int nb = 0; nb < 2; ++nb)
          acc[mb][nb] = __builtin_amdgcn_mfma_f32_16x16x32_bf16(af[mb], bfr[nb], acc[mb][nb], 0, 0, 0);
    }
  }
}

// K1: blocks [0,128):   eq  = exp2(query @ (C2*W_s)^T) -> f32 [b*T+t][h]
//     blocks [128,384): eh  = exp2(enc @ (C2*W_h)^T)   -> bf16 PACKED [b][h/8][s][h%8]
//     blocks [384,640): P^T = (enc @ W_out[:,:H]^T)^T  -> bf16 [b][n][s]
__global__ __launch_bounds__(256) void proj_kernel(
    const float* __restrict__ query, const float* __restrict__ enc,
    const float* __restrict__ Ws, const float* __restrict__ Wh,
    const float* __restrict__ Wo, short* __restrict__ wsbase,
    float* __restrict__ eq) {
  __shared__ short As[64 * 64], Bs[64 * 64];
  f32x4 acc[2][2];
#pragma unroll
  for (int i = 0; i < 2; ++i)
#pragma unroll
    for (int j = 0; j < 2; ++j) acc[i][j] = (f32x4){0.f, 0.f, 0.f, 0.f};
  int bid = blockIdx.x;
  int mode; const float* A; const float* W; int ldw; float scale;
  if (bid < 128)      { mode = 0; A = query; W = Ws; ldw = H;     scale = C2;  }
  else if (bid < 384) { mode = 1; bid -= 128; A = enc; W = Wh; ldw = H; scale = C2; }
  else                { mode = 2; bid -= 384; A = enc; W = Wo; ldw = 2 * H; scale = 1.f; }
  const int bm = (bid >> 3) * 64, bn = (bid & 7) * 64;
  gemm_tile<true, true>(A, H, W, ldw, H, scale, bm, bn, As, Bs, acc);

  short* eh_p = wsbase + OFF_EH;
  short* P_t = wsbase + OFF_PT;
  const int lane = threadIdx.x & 63, wave = threadIdx.x >> 6;
  const int wm = wave >> 1, wn = wave & 1, g = lane >> 4, r = lane & 15;
#pragma unroll
  for (int mb = 0; mb < 2; ++mb)
#pragma unroll
    for (int nb = 0; nb < 2; ++nb) {
      const int m0 = bm + wm * 32 + mb * 16 + g * 4;  // base of 4 consecutive rows
      const int col = bn + wn * 32 + nb * 16 + r;
      if (mode == 0) {
#pragma unroll
        for (int i = 0; i < 4; ++i)
          eq[(size_t)(m0 + i) * H + col] = __builtin_amdgcn_exp2f(acc[mb][nb][i]);
      } else if (mode == 1) {
        // rows are s-consecutive within one b (64-row tile stays inside one b)
        const int bb = m0 >> 8, sl = m0 & 255;
        const size_t base = ((size_t)(bb * (H / 8) + (col >> 3)) * S + sl) * 8 + (col & 7);
#pragma unroll
        for (int i = 0; i < 4; ++i)
          eh_p[base + (size_t)i * 8] = f2bf(__builtin_amdgcn_exp2f(acc[mb][nb][i]));
      } else {
        const int bb = m0 >> 8, sl = m0 & 255;
        short4v o;
        o.x = f2bf(acc[mb][nb][0]); o.y = f2bf(acc[mb][nb][1]);
        o.z = f2bf(acc[mb][nb][2]); o.w = f2bf(acc[mb][nb][3]);
        *reinterpret_cast<short4v*>(&P_t[((size_t)bb * H + col) * S + sl]) = o;
      }
    }
}

// K2: scores + softmax -> attn bf16.
// Block = 2 t-rows: 512 thr = 8 waves = 4 s-groups x 2 H-halves; lane owns s=sg*64+lane.
// tanh(q+h) = 1 - 2*rcp(fma(eq,eh,1)); Sum_h v_h dropped (softmax shift-invariance).
// Superchunk = 16 h; ALL streams (eh, q, v) prefetched one superchunk ahead.
__global__ __launch_bounds__(512) void attn_kernel(
    const float* __restrict__ eq, const short* __restrict__ eh_p,
    const float* __restrict__ v, const int* __restrict__ lens,
    short* __restrict__ attn_bf) {
  __shared__ float s_part[2][2][S];            // [half][tt][s]
  __shared__ float red_m[2][4], red_s[2][4];   // [tt][sg]
  const int tid = threadIdx.x, lane = tid & 63;
  const int wu = __builtin_amdgcn_readfirstlane(tid >> 6);  // uniform wave id
  const int sg = wu & 3, half = wu >> 2;
  const int b = blockIdx.x >> 6;               // 64 blocks per batch (T/2)
  const int t0 = (blockIdx.x & 63) * 2;
  const int s = sg * 64 + lane;

  const float* qp0 = eq + (size_t)(b * T + t0) * H + half * (H / 2);  // uniform
  const float* qp1 = qp0 + H;                                          // uniform
  const float* vp = v + half * (H / 2);                                // uniform
  const short8* ep = reinterpret_cast<const short8*>(eh_p) +
                     ((size_t)(b * (H / 8) + half * (H / 16)) * S + s);

  float acc0 = 0.f, acc1 = 0.f;
  short8 e0 = ep[0], e1 = ep[(size_t)S];
  f32x8 qA0 = *reinterpret_cast<const f32x8*>(qp0);
  f32x8 qB0 = *reinterpret_cast<const f32x8*>(qp0 + 8);
  f32x8 qA1 = *reinterpret_cast<const f32x8*>(qp1);
  f32x8 qB1 = *reinterpret_cast<const f32x8*>(qp1 + 8);
  f32x8 vA = *reinterpret_cast<const f32x8*>(vp);
  f32x8 vB = *reinterpret_cast<const f32x8*>(vp + 8);
  for (int it = 0; it < 16; ++it) {
    // prefetch next superchunk (last iter reloads chunk 0; values unused)
    const int nh = (it < 15) ? (it + 1) * 16 : 0;
    const size_t ne = (it < 15) ? (size_t)(2 * it + 2) * S : 0;
    const short8 e0n = ep[ne], e1n = ep[ne + S];
    const f32x8 qA0n = *reinterpret_cast<const f32x8*>(qp0 + nh);
    const f32x8 qB0n = *reinterpret_cast<const f32x8*>(qp0 + nh + 8);
    const f32x8 qA1n = *reinterpret_cast<const f32x8*>(qp1 + nh);
    const f32x8 qB1n = *reinterpret_cast<const f32x8*>(qp1 + nh + 8);
    const f32x8 vAn = *reinterpret_cast<const f32x8*>(vp + nh);
    const f32x8 vBn = *reinterpret_cast<const f32x8*>(vp + nh + 8);
#pragma unroll
    for (int j = 0; j < 8; ++j) {
      const float e = bf2f(e0[j]);
      acc0 = fmaf(vA[j], __builtin_amdgcn_rcpf(fmaf(qA0[j], e, 1.0f)), acc0);
      acc1 = fmaf(vA[j], __builtin_amdgcn_rcpf(fmaf(qA1[j], e, 1.0f)), acc1);
    }
#pragma unroll
    for (int j = 0; j < 8; ++j) {
      const float e = bf2f(e1[j]);
      acc0 = fmaf(vB[j], __builtin_amdgcn_rcpf(fmaf(qB0[j], e, 1.0f)), acc0);
      acc1 = fmaf(vB[j], __builtin_amdgcn_rcpf(fmaf(qB1[j], e, 1.0f)), acc1);
    }
    e0 = e0n; e1 = e1n;
    qA0 = qA0n; qB0 = qB0n; qA1 = qA1n; qB1 = qB1n;
    vA = vAn; vB = vBn;
  }
  s_part[half][0][s] = acc0;
  s_part[half][1][s] = acc1;
  __syncthreads();

  // all 8 waves redundantly finalize (uniform control flow; identical values)
  const int len = lens[b];
  const float a0 = s_part[0][0][s] + s_part[1][0][s];
  const float a1 = s_part[0][1][s] + s_part[1][1][s];
  const float y0 = (s < len) ? (-2.0f * L2E * a0) : -1e30f;  // log2-domain scores
  const float y1 = (s < len) ? (-2.0f * L2E * a1) : -1e30f;
  float m0 = y0, m1 = y1;
#pragma unroll
  for (int off = 32; off > 0; off >>= 1) {
    m0 = fmaxf(m0, __shfl_xor(m0, off));
    m1 = fmaxf(m1, __shfl_xor(m1, off));
  }
  if (lane == 0) { red_m[0][sg] = m0; red_m[1][sg] = m1; }
  __syncthreads();
  const float mt0 = fmaxf(fmaxf(red_m[0][0], red_m[0][1]), fmaxf(red_m[0][2], red_m[0][3]));
  const float mt1 = fmaxf(fmaxf(red_m[1][0], red_m[1][1]), fmaxf(red_m[1][2], red_m[1][3]));
  const float p0 = __builtin_amdgcn_exp2f(y0 - mt0);
  const float p1 = __builtin_amdgcn_exp2f(y1 - mt1);
  float u0 = p0, u1 = p1;
#pragma unroll
  for (int off = 32; off > 0; off >>= 1) {
    u0 += __shfl_xor(u0, off);
    u1 += __shfl_xor(u1, off);
  }
  if (lane == 0) { red_s[0][sg] = u0; red_s[1][sg] = u1; }
  __syncthreads();
  if (half == 0) {
    const float tot0 = red_s[0][0] + red_s[0][1] + red_s[0][2] + red_s[0][3];
    const float tot1 = red_s[1][0] + red_s[1][1] + red_s[1][2] + red_s[1][3];
    attn_bf[(size_t)(b * T + t0) * S + s] = f2bf(p0 * __builtin_amdgcn_rcpf(tot0));
    attn_bf[(size_t)(b * T + t0 + 1) * S + s] = f2bf(p1 * __builtin_amdgcn_rcpf(tot1));
  }
}

// K3: out = tanh(attn @ P^T + query @ W2^T + b_out), f32 out.
//     phase1: A=attn [B*T][S] bf16, Wt=P_t[b] [n][s] bf16, K=S.
//     phase2: A=query f32, Wt=W_out[:,H:] f32, K=H.
__global__ __launch_bounds__(256) void out_kernel(
    const short* __restrict__ attn_bf, const short* __restrict__ P_t,
    const float* __restrict__ query, const float* __restrict__ Wo,
    const float* __restrict__ bias, float* __restrict__ out) {
  __shared__ short As[64 * 64], Bs[64 * 64];
  f32x4 acc[2][2];
#pragma unroll
  for (int i = 0; i < 2; ++i)
#pragma unroll
    for (int j = 0; j < 2; ++j) acc[i][j] = (f32x4){0.f, 0.f, 0.f, 0.f};
  const int bm = (blockIdx.x >> 3) * 64, bn = (blockIdx.x & 7) * 64;
  const int batch = bm >> 7;               // T = 128 rows per batch
  gemm_tile<false, false>(attn_bf, S, P_t + (size_t)batch * H * S, S, S, 1.f,
                          bm, bn, As, Bs, acc);
  gemm_tile<true, true>(query, H, Wo + H, 2 * H, H, 1.f, bm, bn, As, Bs, acc);
  const int lane = threadIdx.x & 63, wave = threadIdx.x >> 6;
  const int wm = wave >> 1, wn = wave & 1, g = lane >> 4, r = lane & 15;
#pragma unroll
  for (int mb = 0; mb < 2; ++mb)
#pragma unroll
    for (int nb = 0; nb < 2; ++nb) {
      const int col = bn + wn * 32 + nb * 16 + r;
      const float bb = bias[col];
#pragma unroll
      for (int i = 0; i < 4; ++i) {
        const int row = bm + wm * 32 + mb * 16 + g * 4 + i;
        out[(size_t)row * H + col] = fast_tanh(acc[mb][nb][i] + bb);
      }
    }
}

extern "C" void kernel_launch(void* const* d_in, const int* in_sizes, int n_in,
                              void* d_out, int out_size, void* d_ws, size_t ws_size,
                              hipStream_t stream) {
  const float* query = (const float*)d_in[0];  // (B,T,H)
  const float* enc = (const float*)d_in[1];    // (B,S,H)
  const int* lens = (const int*)d_in[2];       // (B)
  const float* W_s = (const float*)d_in[3];    // (H,H)
  const float* W_h = (const float*)d_in[4];    // (H,H)
  const float* v = (const float*)d_in[5];      // (H)
  const float* W_out = (const float*)d_in[6];  // (H,2H)
  const float* b_out = (const float*)d_in[7];  // (H)
  float* out = (float*)d_out;                  // (B,T,H)

  short* wsb = (short*)d_ws;
  short* eh_p = wsb + OFF_EH;
  short* P_t = wsb + OFF_PT;
  short* attn_bf = wsb + OFF_ATT;
  float* eq = (float*)(wsb + OFF_EQ);

  proj_kernel<<<640, 256, 0, stream>>>(query, enc, W_s, W_h, W_out, wsb, eq);
  attn_kernel<<<B * T / 2, 512, 0, stream>>>(eq, eh_p, v, lens, attn_bf);
  out_kernel<<<128, 256, 0, stream>>>(attn_bf, P_t, query, W_out, b_out, out);
}

// Round 10
// 48.850 us; speedup vs baseline: 1.8852x; 1.2508x over previous
//
#include <hip/hip_runtime.h>

// Problem constants (fixed by the reference)
constexpr int B = 8, T = 128, S = 256, H = 512;

typedef __attribute__((ext_vector_type(4))) float f32x4;
typedef __attribute__((ext_vector_type(8))) float f32x8;
typedef __attribute__((ext_vector_type(8))) short short8;
typedef __attribute__((ext_vector_type(4))) short short4v;

#define DEVINL __device__ __forceinline__

DEVINL float bf2f(short s) {
  union { unsigned u; float f; } x;
  x.u = ((unsigned)(unsigned short)s) << 16;
  return x.f;
}
// fp32 -> bf16 round-to-nearest-even (finite inputs)
DEVINL short f2bf(float f) {
  unsigned u = __float_as_uint(f);
  return (short)((u + 0x7fffu + ((u >> 16) & 1u)) >> 16);
}
DEVINL float fast_tanh(float x) {
  float e = __builtin_amdgcn_exp2f(x * 2.8853900817779268f);
  return 1.0f - 2.0f * __builtin_amdgcn_rcpf(e + 1.0f);
}

constexpr float C2 = 2.8853900817779268f;   // 2*log2(e) — folded into W_s, W_h at prep
constexpr float L2E = 1.4426950408889634f;  // log2(e)

// ---- workspace layout (units: shorts) — ~11.5 MiB ----
constexpr size_t OFF_EH  = 0;                               // exp2(hs') PACKED [b][h/8][s][8] bf16 (B*H*S)
constexpr size_t OFF_PT  = OFF_EH + (size_t)B * H * S;      // P^T = (enc@W1^T)^T bf16 [b][n][s] (B*H*S)
constexpr size_t OFF_ATT = OFF_PT + (size_t)B * H * S;      // attn bf16    (B*T*S)
constexpr size_t OFF_QBF = OFF_ATT + (size_t)B * T * S;     // query bf16   (B*T*H)
constexpr size_t OFF_EBF = OFF_QBF + (size_t)B * T * H;     // enc bf16     (B*S*H)
constexpr size_t OFF_WSB = OFF_EBF + (size_t)B * S * H;     // C2*W_s bf16  (H*H)
constexpr size_t OFF_WHB = OFF_WSB + (size_t)H * H;         // C2*W_h bf16  (H*H)
constexpr size_t OFF_WOB = OFF_WHB + (size_t)H * H;         // W_out bf16   (H*2H)
constexpr size_t OFF_EQ  = OFF_WOB + (size_t)H * 2 * H;     // exp2(qs') f32 (B*T*H floats)

// ---- prep: one-time f32 -> bf16 of all GEMM operands (W_s,W_h pre-scaled by C2).
// vec4 counts: q 131072 | e 262144 | Ws 65536 | Wh 65536 | Wo 131072 ; cum 131072,393216,458752,524288,655360
__global__ __launch_bounds__(256) void prep_kernel(
    const float* __restrict__ q, const float* __restrict__ e,
    const float* __restrict__ ws, const float* __restrict__ wh,
    const float* __restrict__ wo, short* __restrict__ base) {
  int vi = blockIdx.x * 256 + threadIdx.x;
  if (vi >= 655360) return;
  const float* src; short* dst; int local; float scale;
  if (vi < 131072)      { src = q;  dst = base + OFF_QBF; local = vi;          scale = 1.f; }
  else if (vi < 393216) { src = e;  dst = base + OFF_EBF; local = vi - 131072; scale = 1.f; }
  else if (vi < 458752) { src = ws; dst = base + OFF_WSB; local = vi - 393216; scale = C2;  }
  else if (vi < 524288) { src = wh; dst = base + OFF_WHB; local = vi - 458752; scale = C2;  }
  else                  { src = wo; dst = base + OFF_WOB; local = vi - 524288; scale = 1.f; }
  float4 f = reinterpret_cast<const float4*>(src)[local];
  short4v o;
  o.x = f2bf(f.x * scale); o.y = f2bf(f.y * scale);
  o.z = f2bf(f.z * scale); o.w = f2bf(f.w * scale);
  *reinterpret_cast<short4v*>(dst + (size_t)local * 4) = o;
}

// ---- MFMA GEMM core, all-bf16 staging (no conversion VALU).
// Tile (MB*32) x 64, 256 thr (4 waves 2x2), BK=64, XOR-swizzled LDS.
// C[m][n] = sum_k A[m][k] * Wt[n][k]; acc laid out [MB][2] flattened. ----
template <int MB>
DEVINL void gemm_tile_bf(const short* __restrict__ A, int lda,
                         const short* __restrict__ Wt, int ldw, int K,
                         int bm, int bn, short* As, short* Bs, f32x4* acc) {
  const int tid = threadIdx.x;
  const int lane = tid & 63;
  const int wm = (tid >> 6) >> 1, wn = (tid >> 6) & 1;
  const int g = lane >> 4, r = lane & 15;
  for (int k0 = 0; k0 < K; k0 += 64) {
    __syncthreads();
#pragma unroll
    for (int p = 0; p < MB; ++p) {     // stage A: MB*32 rows x 8 chunks
      const int idx = p * 256 + tid;
      const int row = idx >> 3, c = idx & 7;
      short8 av = *reinterpret_cast<const short8*>(&A[(size_t)(bm + row) * lda + k0 + c * 8]);
      *reinterpret_cast<short8*>(&As[row * 64 + ((c ^ (row & 7)) * 8)]) = av;
    }
#pragma unroll
    for (int p = 0; p < 2; ++p) {      // stage B: 64 rows x 8 chunks
      const int idx = p * 256 + tid;
      const int row = idx >> 3, c = idx & 7;
      short8 wv = *reinterpret_cast<const short8*>(&Wt[(size_t)(bn + row) * ldw + k0 + c * 8]);
      *reinterpret_cast<short8*>(&Bs[row * 64 + ((c ^ (row & 7)) * 8)]) = wv;
    }
    __syncthreads();
#pragma unroll
    for (int kc = 0; kc < 2; ++kc) {
      short8 af[MB], bfr[2];
#pragma unroll
      for (int mb = 0; mb < MB; ++mb) {
        const int ra = wm * (MB * 16) + mb * 16 + r;
        af[mb] = *reinterpret_cast<const short8*>(&As[ra * 64 + (((kc * 4 + g) ^ (r & 7)) * 8)]);
      }
#pragma unroll
      for (int nb = 0; nb < 2; ++nb) {
        const int rb = wn * 32 + nb * 16 + r;
        bfr[nb] = *reinterpret_cast<const short8*>(&Bs[rb * 64 + (((kc * 4 + g) ^ (r & 7)) * 8)]);
      }
#pragma unroll
      for (int mb = 0; mb < MB; ++mb)
#pragma unroll
        for (int nb = 0; nb < 2; ++nb)
          acc[mb * 2 + nb] =
              __builtin_amdgcn_mfma_f32_16x16x32_bf16(af[mb], bfr[nb], acc[mb * 2 + nb], 0, 0, 0);
    }
  }
}

// K2: blocks [0,128):   eq  = exp2(q_bf @ (C2*W_s)^T) -> f32 [b*T+t][h]
//     blocks [128,384): eh  = exp2(e_bf @ (C2*W_h)^T) -> bf16 PACKED [b][h/8][s][h%8]
//     blocks [384,640): P^T = (e_bf @ Wo[:,:H]^T)^T   -> bf16 [b][n][s]
__global__ __launch_bounds__(256) void proj_kernel(short* __restrict__ wsbase,
                                                   float* __restrict__ eq) {
  __shared__ short As[64 * 64], Bs[64 * 64];
  f32x4 acc[4];
#pragma unroll
  for (int i = 0; i < 4; ++i) acc[i] = (f32x4){0.f, 0.f, 0.f, 0.f};
  int bid = blockIdx.x;
  int mode; const short* A; const short* W; int ldw;
  const short* q_bf = wsbase + OFF_QBF;
  const short* e_bf = wsbase + OFF_EBF;
  if (bid < 128)      { mode = 0; A = q_bf; W = wsbase + OFF_WSB; ldw = H; }
  else if (bid < 384) { mode = 1; bid -= 128; A = e_bf; W = wsbase + OFF_WHB; ldw = H; }
  else                { mode = 2; bid -= 384; A = e_bf; W = wsbase + OFF_WOB; ldw = 2 * H; }
  const int bm = (bid >> 3) * 64, bn = (bid & 7) * 64;
  gemm_tile_bf<2>(A, H, W, ldw, H, bm, bn, As, Bs, acc);

  short* eh_p = wsbase + OFF_EH;
  short* P_t = wsbase + OFF_PT;
  const int lane = threadIdx.x & 63, wave = threadIdx.x >> 6;
  const int wm = wave >> 1, wn = wave & 1, g = lane >> 4, r = lane & 15;
#pragma unroll
  for (int mb = 0; mb < 2; ++mb)
#pragma unroll
    for (int nb = 0; nb < 2; ++nb) {
      const f32x4 a4 = acc[mb * 2 + nb];
      const int m0 = bm + wm * 32 + mb * 16 + g * 4;  // base of 4 consecutive rows
      const int col = bn + wn * 32 + nb * 16 + r;
      if (mode == 0) {
#pragma unroll
        for (int i = 0; i < 4; ++i)
          eq[(size_t)(m0 + i) * H + col] = __builtin_amdgcn_exp2f(a4[i]);
      } else if (mode == 1) {
        // rows are s-consecutive within one b (64-row tile stays inside one b)
        const int bb = m0 >> 8, sl = m0 & 255;
        const size_t base = ((size_t)(bb * (H / 8) + (col >> 3)) * S + sl) * 8 + (col & 7);
#pragma unroll
        for (int i = 0; i < 4; ++i)
          eh_p[base + (size_t)i * 8] = f2bf(__builtin_amdgcn_exp2f(a4[i]));
      } else {
        const int bb = m0 >> 8, sl = m0 & 255;
        short4v o;
        o.x = f2bf(a4[0]); o.y = f2bf(a4[1]); o.z = f2bf(a4[2]); o.w = f2bf(a4[3]);
        *reinterpret_cast<short4v*>(&P_t[((size_t)bb * H + col) * S + sl]) = o;
      }
    }
}

// K3: scores + softmax -> attn bf16.
// Block = 2 t-rows: 512 thr = 8 waves = 4 s-groups x 2 H-halves; lane owns s=sg*64+lane.
// tanh(q+h) = 1 - 2*rcp(fma(eq,eh,1)); Sum_h v_h dropped (softmax shift-invariance).
// Superchunk = 16 h; ALL streams (eh, q, v) prefetched one superchunk ahead.
__global__ __launch_bounds__(512) void attn_kernel(
    const float* __restrict__ eq, const short* __restrict__ eh_p,
    const float* __restrict__ v, const int* __restrict__ lens,
    short* __restrict__ attn_bf) {
  __shared__ float s_part[2][2][S];            // [half][tt][s]
  __shared__ float red_m[2][4], red_s[2][4];   // [tt][sg]
  const int tid = threadIdx.x, lane = tid & 63;
  const int wu = __builtin_amdgcn_readfirstlane(tid >> 6);  // uniform wave id
  const int sg = wu & 3, half = wu >> 2;
  const int b = blockIdx.x >> 6;               // 64 blocks per batch (T/2)
  const int t0 = (blockIdx.x & 63) * 2;
  const int s = sg * 64 + lane;

  const float* qp0 = eq + (size_t)(b * T + t0) * H + half * (H / 2);  // uniform
  const float* qp1 = qp0 + H;                                          // uniform
  const float* vp = v + half * (H / 2);                                // uniform
  const short8* ep = reinterpret_cast<const short8*>(eh_p) +
                     ((size_t)(b * (H / 8) + half * (H / 16)) * S + s);

  float acc0 = 0.f, acc1 = 0.f;
  short8 e0 = ep[0], e1 = ep[(size_t)S];
  f32x8 qA0 = *reinterpret_cast<const f32x8*>(qp0);
  f32x8 qB0 = *reinterpret_cast<const f32x8*>(qp0 + 8);
  f32x8 qA1 = *reinterpret_cast<const f32x8*>(qp1);
  f32x8 qB1 = *reinterpret_cast<const f32x8*>(qp1 + 8);
  f32x8 vA = *reinterpret_cast<const f32x8*>(vp);
  f32x8 vB = *reinterpret_cast<const f32x8*>(vp + 8);
  for (int it = 0; it < 16; ++it) {
    // prefetch next superchunk (last iter reloads chunk 0; values unused)
    const int nh = (it < 15) ? (it + 1) * 16 : 0;
    const size_t ne = (it < 15) ? (size_t)(2 * it + 2) * S : 0;
    const short8 e0n = ep[ne], e1n = ep[ne + S];
    const f32x8 qA0n = *reinterpret_cast<const f32x8*>(qp0 + nh);
    const f32x8 qB0n = *reinterpret_cast<const f32x8*>(qp0 + nh + 8);
    const f32x8 qA1n = *reinterpret_cast<const f32x8*>(qp1 + nh);
    const f32x8 qB1n = *reinterpret_cast<const f32x8*>(qp1 + nh + 8);
    const f32x8 vAn = *reinterpret_cast<const f32x8*>(vp + nh);
    const f32x8 vBn = *reinterpret_cast<const f32x8*>(vp + nh + 8);
#pragma unroll
    for (int j = 0; j < 8; ++j) {
      const float e = bf2f(e0[j]);
      acc0 = fmaf(vA[j], __builtin_amdgcn_rcpf(fmaf(qA0[j], e, 1.0f)), acc0);
      acc1 = fmaf(vA[j], __builtin_amdgcn_rcpf(fmaf(qA1[j], e, 1.0f)), acc1);
    }
#pragma unroll
    for (int j = 0; j < 8; ++j) {
      const float e = bf2f(e1[j]);
      acc0 = fmaf(vB[j], __builtin_amdgcn_rcpf(fmaf(qB0[j], e, 1.0f)), acc0);
      acc1 = fmaf(vB[j], __builtin_amdgcn_rcpf(fmaf(qB1[j], e, 1.0f)), acc1);
    }
    e0 = e0n; e1 = e1n;
    qA0 = qA0n; qB0 = qB0n; qA1 = qA1n; qB1 = qB1n;
    vA = vAn; vB = vBn;
  }
  s_part[half][0][s] = acc0;
  s_part[half][1][s] = acc1;
  __syncthreads();

  // all 8 waves redundantly finalize (uniform control flow; identical values)
  const int len = lens[b];
  const float a0 = s_part[0][0][s] + s_part[1][0][s];
  const float a1 = s_part[0][1][s] + s_part[1][1][s];
  const float y0 = (s < len) ? (-2.0f * L2E * a0) : -1e30f;  // log2-domain scores
  const float y1 = (s < len) ? (-2.0f * L2E * a1) : -1e30f;
  float m0 = y0, m1 = y1;
#pragma unroll
  for (int off = 32; off > 0; off >>= 1) {
    m0 = fmaxf(m0, __shfl_xor(m0, off));
    m1 = fmaxf(m1, __shfl_xor(m1, off));
  }
  if (lane == 0) { red_m[0][sg] = m0; red_m[1][sg] = m1; }
  __syncthreads();
  const float mt0 = fmaxf(fmaxf(red_m[0][0], red_m[0][1]), fmaxf(red_m[0][2], red_m[0][3]));
  const float mt1 = fmaxf(fmaxf(red_m[1][0], red_m[1][1]), fmaxf(red_m[1][2], red_m[1][3]));
  const float p0 = __builtin_amdgcn_exp2f(y0 - mt0);
  const float p1 = __builtin_amdgcn_exp2f(y1 - mt1);
  float u0 = p0, u1 = p1;
#pragma unroll
  for (int off = 32; off > 0; off >>= 1) {
    u0 += __shfl_xor(u0, off);
    u1 += __shfl_xor(u1, off);
  }
  if (lane == 0) { red_s[0][sg] = u0; red_s[1][sg] = u1; }
  __syncthreads();
  if (half == 0) {
    const float tot0 = red_s[0][0] + red_s[0][1] + red_s[0][2] + red_s[0][3];
    const float tot1 = red_s[1][0] + red_s[1][1] + red_s[1][2] + red_s[1][3];
    attn_bf[(size_t)(b * T + t0) * S + s] = f2bf(p0 * __builtin_amdgcn_rcpf(tot0));
    attn_bf[(size_t)(b * T + t0 + 1) * S + s] = f2bf(p1 * __builtin_amdgcn_rcpf(tot1));
  }
}

// K4: out = tanh(attn @ P^T + q_bf @ W2^T + b_out), f32 out. 32x64 tiles, 256 blocks.
__global__ __launch_bounds__(256) void out_kernel(
    const short* __restrict__ wsbase, const float* __restrict__ bias,
    float* __restrict__ out) {
  __shared__ short As[32 * 64], Bs[64 * 64];
  f32x4 acc[2];
#pragma unroll
  for (int i = 0; i < 2; ++i) acc[i] = (f32x4){0.f, 0.f, 0.f, 0.f};
  const int bm = (blockIdx.x >> 3) * 32, bn = (blockIdx.x & 7) * 64;
  const int batch = bm >> 7;               // T = 128 rows per batch
  const short* attn_bf = wsbase + OFF_ATT;
  const short* P_t = wsbase + OFF_PT;
  const short* q_bf = wsbase + OFF_QBF;
  const short* Wob = wsbase + OFF_WOB;
  gemm_tile_bf<1>(attn_bf, S, P_t + (size_t)batch * H * S, S, S, bm, bn, As, Bs, acc);
  gemm_tile_bf<1>(q_bf, H, Wob + H, 2 * H, H, bm, bn, As, Bs, acc);
  const int lane = threadIdx.x & 63, wave = threadIdx.x >> 6;
  const int wm = wave >> 1, wn = wave & 1, g = lane >> 4, r = lane & 15;
#pragma unroll
  for (int nb = 0; nb < 2; ++nb) {
    const f32x4 a4 = acc[nb];
    const int col = bn + wn * 32 + nb * 16 + r;
    const float bb = bias[col];
#pragma unroll
    for (int i = 0; i < 4; ++i) {
      const int row = bm + wm * 16 + g * 4 + i;
      out[(size_t)row * H + col] = fast_tanh(a4[i] + bb);
    }
  }
}

extern "C" void kernel_launch(void* const* d_in, const int* in_sizes, int n_in,
                              void* d_out, int out_size, void* d_ws, size_t ws_size,
                              hipStream_t stream) {
  const float* query = (const float*)d_in[0];  // (B,T,H)
  const float* enc = (const float*)d_in[1];    // (B,S,H)
  const int* lens = (const int*)d_in[2];       // (B)
  const float* W_s = (const float*)d_in[3];    // (H,H)
  const float* W_h = (const float*)d_in[4];    // (H,H)
  const float* v = (const float*)d_in[5];      // (H)
  const float* W_out = (const float*)d_in[6];  // (H,2H)
  const float* b_out = (const float*)d_in[7];  // (H)
  float* out = (float*)d_out;                  // (B,T,H)

  short* wsb = (short*)d_ws;
  short* eh_p = wsb + OFF_EH;
  short* attn_bf = wsb + OFF_ATT;
  float* eq = (float*)(wsb + OFF_EQ);

  prep_kernel<<<2560, 256, 0, stream>>>(query, enc, W_s, W_h, W_out, wsb);
  proj_kernel<<<640, 256, 0, stream>>>(wsb, eq);
  attn_kernel<<<B * T / 2, 512, 0, stream>>>(eq, eh_p, v, lens, attn_bf);
  out_kernel<<<256, 256, 0, stream>>>(wsb, b_out, out);
}